// Round 1
// baseline (502.786 us; speedup 1.0000x reference)
//
#include <hip/hip_runtime.h>

typedef unsigned short u16;
typedef short short8 __attribute__((ext_vector_type(8)));
typedef float f32x4 __attribute__((ext_vector_type(4)));

// ---------- bf16 helpers (no hip_bf16.h dependency) ----------
__device__ __forceinline__ u16 f2b(float f) {
  unsigned u = __float_as_uint(f);
  return (u16)((u + 0x7fffu + ((u >> 16) & 1u)) >> 16);   // RNE
}
__device__ __forceinline__ float b2f(u16 h) {
  return __uint_as_float((unsigned)h << 16);
}

// ---------- problem constants ----------
#define BB 8
#define SS 4096
#define DD 256
#define NWIN 8
#define WIN 512
#define NH 2
#define KD 256
#define DFF 1024
#define MTOK (BB*SS)          // 32768 tokens

// ---------- workspace offsets (bytes) ----------
#define OFF_WQKVT  ((size_t)0)           // bf16 [1536][256]
#define OFF_WOT    ((size_t)786432)      // bf16 [256][512]
#define OFF_W1T    ((size_t)1048576)     // bf16 [1024][256]
#define OFF_W2T    ((size_t)1572864)     // bf16 [256][1024]
#define OFF_BQKV   ((size_t)2097152)     // f32  [1536]
#define OFF_XB     ((size_t)2103296)     // bf16 [32768][256]
#define OFF_QKV    ((size_t)18880512)    // bf16 [32768][1536]
#define OFF_Y      ((size_t)18880512)    // f32  [32768][256]   (alias, after QKV dead)
#define OFF_YB     ((size_t)52434944)    // bf16 [32768][256]   (alias)
#define OFF_HB     ((size_t)69212160)    // bf16 [32768][1024]  (alias)
#define OFF_VT     ((size_t)119543808)   // bf16 [128][256][512]
#define OFF_CTX    ((size_t)153098240)   // bf16 [32768][512]
#define OFF_TMP    ((size_t)186652672)   // f32  [32768][256]

// ---------------------------------------------------------------------------
// cast x (f32) -> bf16, vectorized
__global__ __launch_bounds__(256) void cast_x_kernel(const float* __restrict__ x,
                                                     u16* __restrict__ xb) {
  size_t i = ((size_t)blockIdx.x * 256 + threadIdx.x) * 4;
  float4 v = *(const float4*)(x + i);
  ushort4 o;
  o.x = f2b(v.x); o.y = f2b(v.y); o.z = f2b(v.z); o.w = f2b(v.w);
  *(ushort4*)(xb + i) = o;
}

// ---------------------------------------------------------------------------
// weight prep: transpose to [N][K] bf16 + concat QKV bias (f32)
__global__ __launch_bounds__(256) void prep_w_kernel(
    const float* __restrict__ Wq, const float* __restrict__ Wk, const float* __restrict__ Wv,
    const float* __restrict__ Wo, const float* __restrict__ W1, const float* __restrict__ W2,
    const float* __restrict__ bq, const float* __restrict__ bk, const float* __restrict__ bv,
    u16* __restrict__ wqkvt, u16* __restrict__ wot, u16* __restrict__ w1t,
    u16* __restrict__ w2t, float* __restrict__ bqkv)
{
  for (int i = blockIdx.x * 256 + threadIdx.x; i < 1050112; i += 1024 * 256) {
    if (i < 393216) {                       // WQKVT [1536][256]: n=(qkv,h,k)
      int n = i >> 8, d = i & 255;
      const float* W = (n < 512) ? Wq : (n < 1024) ? Wk : Wv;
      int nn = n & 511;
      wqkvt[i] = f2b(W[d * 512 + nn]);
    } else if (i < 524288) {                // WOT [256][512]
      int j = i - 393216;
      int dout = j >> 9, hk = j & 511;
      wot[j] = f2b(Wo[hk * 256 + dout]);
    } else if (i < 786432) {                // W1T [1024][256]
      int j = i - 524288;
      int f = j >> 8, d = j & 255;
      w1t[j] = f2b(W1[d * 1024 + f]);
    } else if (i < 1048576) {               // W2T [256][1024]
      int j = i - 786432;
      int d = j >> 10, f = j & 1023;
      w2t[j] = f2b(W2[f * 256 + d]);
    } else {                                // bias concat [1536]
      int n = i - 1048576;
      bqkv[n] = (n < 512) ? bq[n] : (n < 1024) ? bk[n - 512] : bv[n - 1024];
    }
  }
}

// ---------------------------------------------------------------------------
// m97-style GEMM: C[M,N] = A[M,K](bf16) * BT[N,K](bf16)^T + bias, opt relu.
// 128x128 tile, BK=32, 256 thr (4 waves, each 64x64 = 4x4 MFMA tiles).
__global__ __launch_bounds__(256) void gemm_bt(
    const u16* __restrict__ A, const u16* __restrict__ BT,
    const float* __restrict__ bias, float* __restrict__ Cf, u16* __restrict__ Cb,
    int M, int N, int K, int relu)
{
  __shared__ __align__(16) u16 As[128 * 32];
  __shared__ __align__(16) u16 Bs[128 * 32];
  const int tid = threadIdx.x, lane = tid & 63, wid = tid >> 6;
  const int ln = lane & 15, quad = lane >> 4;
  const int nb = N >> 7;
  const long bm = (long)(blockIdx.x / nb) << 7;
  const long bn = (long)(blockIdx.x % nb) << 7;
  const int srow = lane >> 2;        // 16 rows per wave per staging chunk
  const int skk  = (lane & 3) << 3;  // 4 x 8-elem (16B) segments per row
  const int wm = (wid >> 1) << 6, wn = (wid & 1) << 6;

  f32x4 acc[4][4];
#pragma unroll
  for (int i = 0; i < 4; i++)
#pragma unroll
    for (int j = 0; j < 4; j++) acc[i][j] = (f32x4){0.f, 0.f, 0.f, 0.f};

  for (int kt = 0; kt < K; kt += 32) {
    __syncthreads();
#pragma unroll
    for (int i = 0; i < 2; i++) {
      const int rr = i * 64 + wid * 16 + srow;
      __builtin_amdgcn_global_load_lds(
          (const __attribute__((address_space(1))) void*)(A + (size_t)(bm + rr) * K + kt + skk),
          (__attribute__((address_space(3))) void*)(As + (size_t)(i * 64 + wid * 16) * 32),
          16, 0, 0);
      __builtin_amdgcn_global_load_lds(
          (const __attribute__((address_space(1))) void*)(BT + (size_t)(bn + rr) * K + kt + skk),
          (__attribute__((address_space(3))) void*)(Bs + (size_t)(i * 64 + wid * 16) * 32),
          16, 0, 0);
    }
    __syncthreads();
    short8 a[4], b[4];
#pragma unroll
    for (int i = 0; i < 4; i++) a[i] = *(const short8*)(As + (wm + i * 16 + ln) * 32 + quad * 8);
#pragma unroll
    for (int j = 0; j < 4; j++) b[j] = *(const short8*)(Bs + (wn + j * 16 + ln) * 32 + quad * 8);
#pragma unroll
    for (int i = 0; i < 4; i++)
#pragma unroll
      for (int j = 0; j < 4; j++)
        acc[i][j] = __builtin_amdgcn_mfma_f32_16x16x32_bf16(a[i], b[j], acc[i][j], 0, 0, 0);
  }

#pragma unroll
  for (int i = 0; i < 4; i++)
#pragma unroll
    for (int j = 0; j < 4; j++) {
      const long row0 = bm + wm + i * 16 + quad * 4;
      const long col  = bn + wn + j * 16 + ln;
      const float bb = bias ? bias[col] : 0.f;
#pragma unroll
      for (int r = 0; r < 4; r++) {
        float v = acc[i][j][r] + bb;
        if (relu) v = fmaxf(v, 0.f);
        const size_t off = (size_t)(row0 + r) * N + col;
        if (Cf) Cf[off] = v;
        if (Cb) Cb[off] = f2b(v);
      }
    }
}

// ---------------------------------------------------------------------------
// V transpose: QKV[t][1024 + h*256 + k] -> VT[blk][k][t], 64x64 tiles via LDS
__global__ __launch_bounds__(256) void transpose_v(const u16* __restrict__ qkv,
                                                   u16* __restrict__ vt)
{
  __shared__ u16 tile[64][72];
  const int bid = blockIdx.x;                 // 128 * 8 * 4
  const int kt4 = bid & 3, tt = (bid >> 2) & 7, blk = bid >> 5;
  const int bw = blk >> 1, h = blk & 1;
  const int lk = threadIdx.x & 63, l0 = threadIdx.x >> 6;
#pragma unroll
  for (int i = 0; i < 16; i++) {
    const int lt = l0 + i * 4;
    tile[lt][lk] = qkv[(size_t)(bw * 512 + tt * 64 + lt) * 1536 + 1024 + h * 256 + kt4 * 64 + lk];
  }
  __syncthreads();
#pragma unroll
  for (int i = 0; i < 16; i++) {
    const int kk = l0 + i * 4;
    vt[((size_t)blk * 256 + kt4 * 64 + kk) * 512 + tt * 64 + lk] = tile[lk][kk];
  }
}

// ---------------------------------------------------------------------------
// windowed attention: per WG = (b,w,h) block x 32-row Q tile.
// Stage1 S=Q K^T (MFMA, frags straight from global), S bf16 in LDS;
// Stage2 exact softmax over 512 (in-place, register-staged);
// Stage3 ctx = P V via VT (MFMA).
__global__ __launch_bounds__(256) void attn_kernel(
    const u16* __restrict__ qkv, const u16* __restrict__ vt, u16* __restrict__ ctx)
{
  __shared__ __align__(16) u16 Sl[32 * 520];   // 33280 B
  const int bid = blockIdx.x;                  // 2048
  // swizzle: all 16 q-tiles of one (b,w,h) land on one XCD (bid%8 round robin)
  const int xcd = bid & 7;
  const int s   = bid >> 3;
  const int blk = xcd + ((s >> 4) << 3);       // 0..127 = (b*8+w)*2 + h
  const int qt  = s & 15;
  const int bw = blk >> 1, h = blk & 1;
  const size_t tb = (size_t)bw * 512;
  const int s0 = qt * 32;

  const int tid = threadIdx.x, lane = tid & 63, wid = tid >> 6;
  const int ln = lane & 15, quad = lane >> 4;

  // ---- Stage 1 ----
  {
    const int wn = wid * 128;
    f32x4 acc[2][8];
#pragma unroll
    for (int i = 0; i < 2; i++)
#pragma unroll
      for (int j = 0; j < 8; j++) acc[i][j] = (f32x4){0.f, 0.f, 0.f, 0.f};
    const u16* Qb = qkv + (tb + s0) * 1536 + h * 256;
    const u16* Kb = qkv + tb * 1536 + 512 + h * 256;
    for (int kt = 0; kt < 256; kt += 32) {
      short8 a0 = *(const short8*)(Qb + (size_t)ln * 1536 + kt + quad * 8);
      short8 a1 = *(const short8*)(Qb + (size_t)(16 + ln) * 1536 + kt + quad * 8);
#pragma unroll
      for (int j = 0; j < 8; j++) {
        short8 b = *(const short8*)(Kb + (size_t)(wn + j * 16 + ln) * 1536 + kt + quad * 8);
        acc[0][j] = __builtin_amdgcn_mfma_f32_16x16x32_bf16(a0, b, acc[0][j], 0, 0, 0);
        acc[1][j] = __builtin_amdgcn_mfma_f32_16x16x32_bf16(a1, b, acc[1][j], 0, 0, 0);
      }
    }
#pragma unroll
    for (int i = 0; i < 2; i++)
#pragma unroll
      for (int j = 0; j < 8; j++)
#pragma unroll
        for (int r = 0; r < 4; r++)
          Sl[(i * 16 + quad * 4 + r) * 520 + wn + j * 16 + ln] = f2b(acc[i][j][r]);
  }
  __syncthreads();

  // ---- Stage 2: softmax(S/16) row-wise, rows of 512, 8 lanes per row ----
  {
    const int row = tid >> 3, sub = tid & 7;
    u16* Rp = Sl + row * 520;
    float vals[64];
    float m = -1e30f;
#pragma unroll
    for (int i = 0; i < 32; i++) {
      unsigned v = *(const unsigned*)(Rp + (sub + 8 * i) * 2);
      float lo = __uint_as_float(v << 16);
      float hi = __uint_as_float(v & 0xffff0000u);
      vals[2 * i] = lo; vals[2 * i + 1] = hi;
      m = fmaxf(m, fmaxf(lo, hi));
    }
    m = fmaxf(m, __shfl_xor(m, 1));
    m = fmaxf(m, __shfl_xor(m, 2));
    m = fmaxf(m, __shfl_xor(m, 4));
    const float sc = 0.0625f;    // 1/sqrt(256)
    float sum = 0.f;
#pragma unroll
    for (int i = 0; i < 64; i++) {
      float e = __expf((vals[i] - m) * sc);
      vals[i] = e; sum += e;
    }
    sum += __shfl_xor(sum, 1);
    sum += __shfl_xor(sum, 2);
    sum += __shfl_xor(sum, 4);
    const float inv = 1.f / sum;
#pragma unroll
    for (int i = 0; i < 32; i++) {
      unsigned pv = ((unsigned)f2b(vals[2 * i + 1] * inv) << 16) | f2b(vals[2 * i] * inv);
      *(unsigned*)(Rp + (sub + 8 * i) * 2) = pv;
    }
  }
  __syncthreads();

  // ---- Stage 3 ----
  {
    const int wn = wid * 64;
    const u16* Vb = vt + (size_t)blk * 131072;   // [256][512]
    f32x4 o[2][4];
#pragma unroll
    for (int i = 0; i < 2; i++)
#pragma unroll
      for (int j = 0; j < 4; j++) o[i][j] = (f32x4){0.f, 0.f, 0.f, 0.f};
    for (int kt = 0; kt < 512; kt += 32) {
      short8 a0 = *(const short8*)(Sl + (size_t)ln * 520 + kt + quad * 8);
      short8 a1 = *(const short8*)(Sl + (size_t)(16 + ln) * 520 + kt + quad * 8);
#pragma unroll
      for (int j = 0; j < 4; j++) {
        short8 b = *(const short8*)(Vb + (size_t)(wn + j * 16 + ln) * 512 + kt + quad * 8);
        o[0][j] = __builtin_amdgcn_mfma_f32_16x16x32_bf16(a0, b, o[0][j], 0, 0, 0);
        o[1][j] = __builtin_amdgcn_mfma_f32_16x16x32_bf16(a1, b, o[1][j], 0, 0, 0);
      }
    }
#pragma unroll
    for (int i = 0; i < 2; i++)
#pragma unroll
      for (int j = 0; j < 4; j++) {
        const size_t trow = tb + s0 + i * 16 + quad * 4;
#pragma unroll
        for (int r = 0; r < 4; r++)
          ctx[(trow + r) * 512 + h * 256 + wn + j * 16 + ln] = f2b(o[i][j][r]);
      }
  }
}

// ---------------------------------------------------------------------------
// residual add + LayerNorm over D=256; one row per wave; writes f32 (+bf16 opt)
__global__ __launch_bounds__(256) void ln_kernel(
    const float* __restrict__ add_in, const float* __restrict__ resid,
    const float* __restrict__ g, const float* __restrict__ beta,
    float* __restrict__ yout, u16* __restrict__ ybout)
{
  const int row = blockIdx.x * 4 + (threadIdx.x >> 6);
  const int lane = threadIdx.x & 63;
  const size_t base = (size_t)row * 256 + lane * 4;
  const float4 a = *(const float4*)(add_in + base);
  const float4 r = *(const float4*)(resid + base);
  float4 v;
  v.x = a.x + r.x; v.y = a.y + r.y; v.z = a.z + r.z; v.w = a.w + r.w;
  float s = v.x + v.y + v.z + v.w;
  float q = v.x * v.x + v.y * v.y + v.z * v.z + v.w * v.w;
#pragma unroll
  for (int o = 32; o; o >>= 1) { s += __shfl_xor(s, o); q += __shfl_xor(q, o); }
  const float mu = s * (1.f / 256.f);
  const float var = q * (1.f / 256.f) - mu * mu;
  const float inv = rsqrtf(var + 1e-3f);
  const float4 gg = *(const float4*)(g + lane * 4);
  const float4 bb = *(const float4*)(beta + lane * 4);
  float4 o4;
  o4.x = (v.x - mu) * inv * gg.x + bb.x;
  o4.y = (v.y - mu) * inv * gg.y + bb.y;
  o4.z = (v.z - mu) * inv * gg.z + bb.z;
  o4.w = (v.w - mu) * inv * gg.w + bb.w;
  if (yout) *(float4*)(yout + base) = o4;
  if (ybout) {
    ushort4 ob;
    ob.x = f2b(o4.x); ob.y = f2b(o4.y); ob.z = f2b(o4.z); ob.w = f2b(o4.w);
    *(ushort4*)(ybout + base) = ob;
  }
}

// ---------------------------------------------------------------------------
extern "C" void kernel_launch(void* const* d_in, const int* in_sizes, int n_in,
                              void* d_out, int out_size, void* d_ws, size_t ws_size,
                              hipStream_t stream) {
  (void)in_sizes; (void)n_in; (void)out_size; (void)ws_size;
  const float* x    = (const float*)d_in[0];
  const float* Wq   = (const float*)d_in[1];
  const float* bq   = (const float*)d_in[2];
  const float* Wk   = (const float*)d_in[3];
  const float* bk   = (const float*)d_in[4];
  const float* Wv   = (const float*)d_in[5];
  const float* bv   = (const float*)d_in[6];
  const float* Wo   = (const float*)d_in[7];
  const float* bo   = (const float*)d_in[8];
  const float* ln1g = (const float*)d_in[9];
  const float* ln1b = (const float*)d_in[10];
  const float* W1   = (const float*)d_in[11];
  const float* b1   = (const float*)d_in[12];
  const float* W2   = (const float*)d_in[13];
  const float* b2   = (const float*)d_in[14];
  const float* ln2g = (const float*)d_in[15];
  const float* ln2b = (const float*)d_in[16];
  float* out = (float*)d_out;

  char* ws = (char*)d_ws;
  u16*   WQKVT = (u16*)(ws + OFF_WQKVT);
  u16*   WOT   = (u16*)(ws + OFF_WOT);
  u16*   W1T   = (u16*)(ws + OFF_W1T);
  u16*   W2T   = (u16*)(ws + OFF_W2T);
  float* BQKV  = (float*)(ws + OFF_BQKV);
  u16*   XB    = (u16*)(ws + OFF_XB);
  u16*   QKV   = (u16*)(ws + OFF_QKV);
  float* Y     = (float*)(ws + OFF_Y);
  u16*   YB    = (u16*)(ws + OFF_YB);
  u16*   HB    = (u16*)(ws + OFF_HB);
  u16*   VT    = (u16*)(ws + OFF_VT);
  u16*   CTX   = (u16*)(ws + OFF_CTX);
  float* TMP   = (float*)(ws + OFF_TMP);

  // 1) casts / weight prep
  cast_x_kernel<<<8192, 256, 0, stream>>>(x, XB);
  prep_w_kernel<<<1024, 256, 0, stream>>>(Wq, Wk, Wv, Wo, W1, W2, bq, bk, bv,
                                          WQKVT, WOT, W1T, W2T, BQKV);
  // 2) QKV projection: [32768,256] x [256,1536]
  gemm_bt<<<3072, 256, 0, stream>>>(XB, WQKVT, BQKV, nullptr, QKV,
                                    MTOK, 1536, 256, 0);
  // 3) V transpose per (b,w,h)
  transpose_v<<<4096, 256, 0, stream>>>(QKV, VT);
  // 4) windowed attention
  attn_kernel<<<2048, 256, 0, stream>>>(QKV, VT, CTX);
  // 5) output projection: [32768,512] x [512,256]
  gemm_bt<<<512, 256, 0, stream>>>(CTX, WOT, bo, TMP, nullptr,
                                   MTOK, 256, 512, 0);
  // 6) residual + LN1 -> Y (f32) + YB (bf16)
  ln_kernel<<<8192, 256, 0, stream>>>(TMP, x, ln1g, ln1b, Y, YB);
  // 7) FF1 + ReLU: [32768,256] x [256,1024]
  gemm_bt<<<2048, 256, 0, stream>>>(YB, W1T, b1, nullptr, HB,
                                    MTOK, 1024, 256, 1);
  // 8) FF2: [32768,1024] x [1024,256]
  gemm_bt<<<512, 256, 0, stream>>>(HB, W2T, b2, TMP, nullptr,
                                   MTOK, 256, 1024, 0);
  // 9) residual + LN2 -> out
  ln_kernel<<<8192, 256, 0, stream>>>(TMP, Y, ln2g, ln2b, out, nullptr);
}

// Round 2
// 456.343 us; speedup vs baseline: 1.1018x; 1.1018x over previous
//
#include <hip/hip_runtime.h>

typedef unsigned short u16;
typedef short short8 __attribute__((ext_vector_type(8)));
typedef float f32x4 __attribute__((ext_vector_type(4)));

// ---------- bf16 helpers (no hip_bf16.h dependency) ----------
__device__ __forceinline__ u16 f2b(float f) {
  unsigned u = __float_as_uint(f);
  return (u16)((u + 0x7fffu + ((u >> 16) & 1u)) >> 16);   // RNE
}
__device__ __forceinline__ float b2f(u16 h) {
  return __uint_as_float((unsigned)h << 16);
}

// ---------- problem constants ----------
#define BB 8
#define SS 4096
#define DD 256
#define NWIN 8
#define WIN 512
#define NH 2
#define KD 256
#define DFF 1024
#define MTOK (BB*SS)          // 32768 tokens

// ---------- workspace offsets (bytes) ----------
#define OFF_WQKVT  ((size_t)0)           // bf16 [1536][256]
#define OFF_WOT    ((size_t)786432)      // bf16 [256][512]
#define OFF_W1T    ((size_t)1048576)     // bf16 [1024][256]
#define OFF_W2T    ((size_t)1572864)     // bf16 [256][1024]
#define OFF_BQKV   ((size_t)2097152)     // f32  [1536]
#define OFF_XB     ((size_t)2103296)     // bf16 [32768][256]
#define OFF_QKV    ((size_t)18880512)    // bf16 [32768][1536]
#define OFF_Y      ((size_t)18880512)    // f32  [32768][256]   (alias, after QKV dead)
#define OFF_YB     ((size_t)52434944)    // bf16 [32768][256]   (alias)
#define OFF_HB     ((size_t)69212160)    // bf16 [32768][1024]  (alias, VT dead)
#define OFF_VT     ((size_t)119543808)   // bf16 [128][256][512]
#define OFF_CTX    ((size_t)153098240)   // bf16 [32768][512]
#define OFF_TMP    ((size_t)186652672)   // f32  [32768][256]
#define OFF_S      ((size_t)186652672)   // bf16 [128][512][512] (alias TMP; S dead before TMP written)

// ---------------------------------------------------------------------------
// cast x (f32) -> bf16, vectorized
__global__ __launch_bounds__(256) void cast_x_kernel(const float* __restrict__ x,
                                                     u16* __restrict__ xb) {
  size_t i = ((size_t)blockIdx.x * 256 + threadIdx.x) * 4;
  float4 v = *(const float4*)(x + i);
  ushort4 o;
  o.x = f2b(v.x); o.y = f2b(v.y); o.z = f2b(v.z); o.w = f2b(v.w);
  *(ushort4*)(xb + i) = o;
}

// ---------------------------------------------------------------------------
// weight prep: transpose to [N][K] bf16 + concat QKV bias (f32)
__global__ __launch_bounds__(256) void prep_w_kernel(
    const float* __restrict__ Wq, const float* __restrict__ Wk, const float* __restrict__ Wv,
    const float* __restrict__ Wo, const float* __restrict__ W1, const float* __restrict__ W2,
    const float* __restrict__ bq, const float* __restrict__ bk, const float* __restrict__ bv,
    u16* __restrict__ wqkvt, u16* __restrict__ wot, u16* __restrict__ w1t,
    u16* __restrict__ w2t, float* __restrict__ bqkv)
{
  for (int i = blockIdx.x * 256 + threadIdx.x; i < 1050112; i += 1024 * 256) {
    if (i < 393216) {                       // WQKVT [1536][256]: n=(qkv,h,k)
      int n = i >> 8, d = i & 255;
      const float* W = (n < 512) ? Wq : (n < 1024) ? Wk : Wv;
      int nn = n & 511;
      wqkvt[i] = f2b(W[d * 512 + nn]);
    } else if (i < 524288) {                // WOT [256][512]
      int j = i - 393216;
      int dout = j >> 9, hk = j & 511;
      wot[j] = f2b(Wo[hk * 256 + dout]);
    } else if (i < 786432) {                // W1T [1024][256]
      int j = i - 524288;
      int f = j >> 8, d = j & 255;
      w1t[j] = f2b(W1[d * 1024 + f]);
    } else if (i < 1048576) {               // W2T [256][1024]
      int j = i - 786432;
      int d = j >> 10, f = j & 1023;
      w2t[j] = f2b(W2[f * 256 + d]);
    } else {                                // bias concat [1536]
      int n = i - 1048576;
      bqkv[n] = (n < 512) ? bq[n] : (n < 1024) ? bk[n - 512] : bv[n - 1024];
    }
  }
}

// ---------------------------------------------------------------------------
// m97-style GEMM: C[M,N] = A[M,K](bf16) * BT[N,K](bf16)^T + bias, opt relu.
// 128x128 tile, BK=32, 256 thr (4 waves, each 64x64 = 4x4 MFMA tiles).
__global__ __launch_bounds__(256) void gemm_bt(
    const u16* __restrict__ A, const u16* __restrict__ BT,
    const float* __restrict__ bias, float* __restrict__ Cf, u16* __restrict__ Cb,
    int M, int N, int K, int relu)
{
  __shared__ __align__(16) u16 As[128 * 32];
  __shared__ __align__(16) u16 Bs[128 * 32];
  const int tid = threadIdx.x, lane = tid & 63, wid = tid >> 6;
  const int ln = lane & 15, quad = lane >> 4;
  const int nb = N >> 7;
  const long bm = (long)(blockIdx.x / nb) << 7;
  const long bn = (long)(blockIdx.x % nb) << 7;
  const int srow = lane >> 2;        // 16 rows per wave per staging chunk
  const int skk  = (lane & 3) << 3;  // 4 x 8-elem (16B) segments per row
  const int wm = (wid >> 1) << 6, wn = (wid & 1) << 6;

  f32x4 acc[4][4];
#pragma unroll
  for (int i = 0; i < 4; i++)
#pragma unroll
    for (int j = 0; j < 4; j++) acc[i][j] = (f32x4){0.f, 0.f, 0.f, 0.f};

  for (int kt = 0; kt < K; kt += 32) {
    __syncthreads();
#pragma unroll
    for (int i = 0; i < 2; i++) {
      const int rr = i * 64 + wid * 16 + srow;
      __builtin_amdgcn_global_load_lds(
          (const __attribute__((address_space(1))) void*)(A + (size_t)(bm + rr) * K + kt + skk),
          (__attribute__((address_space(3))) void*)(As + (size_t)(i * 64 + wid * 16) * 32),
          16, 0, 0);
      __builtin_amdgcn_global_load_lds(
          (const __attribute__((address_space(1))) void*)(BT + (size_t)(bn + rr) * K + kt + skk),
          (__attribute__((address_space(3))) void*)(Bs + (size_t)(i * 64 + wid * 16) * 32),
          16, 0, 0);
    }
    __syncthreads();
    short8 a[4], b[4];
#pragma unroll
    for (int i = 0; i < 4; i++) a[i] = *(const short8*)(As + (wm + i * 16 + ln) * 32 + quad * 8);
#pragma unroll
    for (int j = 0; j < 4; j++) b[j] = *(const short8*)(Bs + (wn + j * 16 + ln) * 32 + quad * 8);
#pragma unroll
    for (int i = 0; i < 4; i++)
#pragma unroll
      for (int j = 0; j < 4; j++)
        acc[i][j] = __builtin_amdgcn_mfma_f32_16x16x32_bf16(a[i], b[j], acc[i][j], 0, 0, 0);
  }

#pragma unroll
  for (int i = 0; i < 4; i++)
#pragma unroll
    for (int j = 0; j < 4; j++) {
      const long row0 = bm + wm + i * 16 + quad * 4;
      const long col  = bn + wn + j * 16 + ln;
      const float bb = bias ? bias[col] : 0.f;
#pragma unroll
      for (int r = 0; r < 4; r++) {
        float v = acc[i][j][r] + bb;
        if (relu) v = fmaxf(v, 0.f);
        const size_t off = (size_t)(row0 + r) * N + col;
        if (Cf) Cf[off] = v;
        if (Cb) Cb[off] = f2b(v);
      }
    }
}

// ---------------------------------------------------------------------------
// batched GEMM over 128 (b,w,h) blocks: C = A * B^T, all bf16, strided rows.
// Per-block base offsets: off = bw*s?bw + h*s?h. Tile 128x128, BK=32, M=512.
// grid = 128 * 4(Mtiles) * Ntiles  (consecutive bids share a block -> L2 reuse)
__global__ __launch_bounds__(256) void bgemm(
    const u16* __restrict__ A, long sAbw, long sAh, int lda,
    const u16* __restrict__ B, long sBbw, long sBh, int ldb,
    u16* __restrict__ C, long sCbw, long sCh, int ldc,
    int K, int Ntiles)
{
  __shared__ __align__(16) u16 As[128 * 32];
  __shared__ __align__(16) u16 Bs[128 * 32];
  const int tid = threadIdx.x, lane = tid & 63, wid = tid >> 6;
  const int ln = lane & 15, quad = lane >> 4;
  const int per = 4 * Ntiles;
  const int blk = blockIdx.x / per;
  const int rem = blockIdx.x % per;
  const int mt = rem / Ntiles, nt = rem % Ntiles;
  const int bw = blk >> 1, h = blk & 1;
  const u16* Ab = A + (size_t)bw * sAbw + (size_t)h * sAh + (size_t)mt * 128 * lda;
  const u16* Bp = B + (size_t)bw * sBbw + (size_t)h * sBh + (size_t)nt * 128 * ldb;
  u16*       Cp = C + (size_t)bw * sCbw + (size_t)h * sCh + (size_t)mt * 128 * ldc + nt * 128;
  const int srow = lane >> 2;
  const int skk  = (lane & 3) << 3;
  const int wm = (wid >> 1) << 6, wn = (wid & 1) << 6;

  f32x4 acc[4][4];
#pragma unroll
  for (int i = 0; i < 4; i++)
#pragma unroll
    for (int j = 0; j < 4; j++) acc[i][j] = (f32x4){0.f, 0.f, 0.f, 0.f};

  for (int kt = 0; kt < K; kt += 32) {
    __syncthreads();
#pragma unroll
    for (int i = 0; i < 2; i++) {
      const int rr = i * 64 + wid * 16 + srow;
      __builtin_amdgcn_global_load_lds(
          (const __attribute__((address_space(1))) void*)(Ab + (size_t)rr * lda + kt + skk),
          (__attribute__((address_space(3))) void*)(As + (size_t)(i * 64 + wid * 16) * 32),
          16, 0, 0);
      __builtin_amdgcn_global_load_lds(
          (const __attribute__((address_space(1))) void*)(Bp + (size_t)rr * ldb + kt + skk),
          (__attribute__((address_space(3))) void*)(Bs + (size_t)(i * 64 + wid * 16) * 32),
          16, 0, 0);
    }
    __syncthreads();
    short8 a[4], b[4];
#pragma unroll
    for (int i = 0; i < 4; i++) a[i] = *(const short8*)(As + (wm + i * 16 + ln) * 32 + quad * 8);
#pragma unroll
    for (int j = 0; j < 4; j++) b[j] = *(const short8*)(Bs + (wn + j * 16 + ln) * 32 + quad * 8);
#pragma unroll
    for (int i = 0; i < 4; i++)
#pragma unroll
      for (int j = 0; j < 4; j++)
        acc[i][j] = __builtin_amdgcn_mfma_f32_16x16x32_bf16(a[i], b[j], acc[i][j], 0, 0, 0);
  }

#pragma unroll
  for (int i = 0; i < 4; i++)
#pragma unroll
    for (int j = 0; j < 4; j++) {
      const int row0 = wm + i * 16 + quad * 4;
      const int col  = wn + j * 16 + ln;
#pragma unroll
      for (int r = 0; r < 4; r++)
        Cp[(size_t)(row0 + r) * ldc + col] = f2b(acc[i][j][r]);
    }
}

// ---------------------------------------------------------------------------
// softmax over rows of 512 (bf16 in/out, in place). One wave per row.
// exp((v - max) / 16), normalized. 65536 rows.
__global__ __launch_bounds__(256) void softmax_kernel(u16* __restrict__ S) {
  const int row = blockIdx.x * 4 + (threadIdx.x >> 6);
  const int lane = threadIdx.x & 63;
  u16* p = S + (size_t)row * 512 + lane * 8;
  short8 v8 = *(const short8*)p;
  float v[8];
  float m = -1e30f;
#pragma unroll
  for (int j = 0; j < 8; j++) { v[j] = b2f((u16)v8[j]); m = fmaxf(m, v[j]); }
#pragma unroll
  for (int o = 32; o; o >>= 1) m = fmaxf(m, __shfl_xor(m, o));
  const float sc = 0.0625f;   // 1/sqrt(256)
  float sum = 0.f;
#pragma unroll
  for (int j = 0; j < 8; j++) { v[j] = __expf((v[j] - m) * sc); sum += v[j]; }
#pragma unroll
  for (int o = 32; o; o >>= 1) sum += __shfl_xor(sum, o);
  const float inv = 1.f / sum;
  short8 r8;
#pragma unroll
  for (int j = 0; j < 8; j++) r8[j] = (short)f2b(v[j] * inv);
  *(short8*)p = r8;
}

// ---------------------------------------------------------------------------
// V transpose: QKV[t][1024 + h*256 + k] -> VT[blk][k][t], 64x64 tiles via LDS
__global__ __launch_bounds__(256) void transpose_v(const u16* __restrict__ qkv,
                                                   u16* __restrict__ vt)
{
  __shared__ u16 tile[64][72];
  const int bid = blockIdx.x;                 // 128 * 8 * 4
  const int kt4 = bid & 3, tt = (bid >> 2) & 7, blk = bid >> 5;
  const int bw = blk >> 1, h = blk & 1;
  const int lk = threadIdx.x & 63, l0 = threadIdx.x >> 6;
#pragma unroll
  for (int i = 0; i < 16; i++) {
    const int lt = l0 + i * 4;
    tile[lt][lk] = qkv[(size_t)(bw * 512 + tt * 64 + lt) * 1536 + 1024 + h * 256 + kt4 * 64 + lk];
  }
  __syncthreads();
#pragma unroll
  for (int i = 0; i < 16; i++) {
    const int kk = l0 + i * 4;
    vt[((size_t)blk * 256 + kt4 * 64 + kk) * 512 + tt * 64 + lk] = tile[lk][kk];
  }
}

// ---------------------------------------------------------------------------
// residual add + LayerNorm over D=256; one row per wave; writes f32 (+bf16 opt)
__global__ __launch_bounds__(256) void ln_kernel(
    const float* __restrict__ add_in, const float* __restrict__ resid,
    const float* __restrict__ g, const float* __restrict__ beta,
    float* __restrict__ yout, u16* __restrict__ ybout)
{
  const int row = blockIdx.x * 4 + (threadIdx.x >> 6);
  const int lane = threadIdx.x & 63;
  const size_t base = (size_t)row * 256 + lane * 4;
  const float4 a = *(const float4*)(add_in + base);
  const float4 r = *(const float4*)(resid + base);
  float4 v;
  v.x = a.x + r.x; v.y = a.y + r.y; v.z = a.z + r.z; v.w = a.w + r.w;
  float s = v.x + v.y + v.z + v.w;
  float q = v.x * v.x + v.y * v.y + v.z * v.z + v.w * v.w;
#pragma unroll
  for (int o = 32; o; o >>= 1) { s += __shfl_xor(s, o); q += __shfl_xor(q, o); }
  const float mu = s * (1.f / 256.f);
  const float var = q * (1.f / 256.f) - mu * mu;
  const float inv = rsqrtf(var + 1e-3f);
  const float4 gg = *(const float4*)(g + lane * 4);
  const float4 bb = *(const float4*)(beta + lane * 4);
  float4 o4;
  o4.x = (v.x - mu) * inv * gg.x + bb.x;
  o4.y = (v.y - mu) * inv * gg.y + bb.y;
  o4.z = (v.z - mu) * inv * gg.z + bb.z;
  o4.w = (v.w - mu) * inv * gg.w + bb.w;
  if (yout) *(float4*)(yout + base) = o4;
  if (ybout) {
    ushort4 ob;
    ob.x = f2b(o4.x); ob.y = f2b(o4.y); ob.z = f2b(o4.z); ob.w = f2b(o4.w);
    *(ushort4*)(ybout + base) = ob;
  }
}

// ---------------------------------------------------------------------------
extern "C" void kernel_launch(void* const* d_in, const int* in_sizes, int n_in,
                              void* d_out, int out_size, void* d_ws, size_t ws_size,
                              hipStream_t stream) {
  (void)in_sizes; (void)n_in; (void)out_size; (void)ws_size;
  const float* x    = (const float*)d_in[0];
  const float* Wq   = (const float*)d_in[1];
  const float* bq   = (const float*)d_in[2];
  const float* Wk   = (const float*)d_in[3];
  const float* bk   = (const float*)d_in[4];
  const float* Wv   = (const float*)d_in[5];
  const float* bv   = (const float*)d_in[6];
  const float* Wo   = (const float*)d_in[7];
  const float* bo   = (const float*)d_in[8];
  const float* ln1g = (const float*)d_in[9];
  const float* ln1b = (const float*)d_in[10];
  const float* W1   = (const float*)d_in[11];
  const float* b1   = (const float*)d_in[12];
  const float* W2   = (const float*)d_in[13];
  const float* b2   = (const float*)d_in[14];
  const float* ln2g = (const float*)d_in[15];
  const float* ln2b = (const float*)d_in[16];
  float* out = (float*)d_out;

  char* ws = (char*)d_ws;
  u16*   WQKVT = (u16*)(ws + OFF_WQKVT);
  u16*   WOT   = (u16*)(ws + OFF_WOT);
  u16*   W1T   = (u16*)(ws + OFF_W1T);
  u16*   W2T   = (u16*)(ws + OFF_W2T);
  float* BQKV  = (float*)(ws + OFF_BQKV);
  u16*   XB    = (u16*)(ws + OFF_XB);
  u16*   QKV   = (u16*)(ws + OFF_QKV);
  float* Y     = (float*)(ws + OFF_Y);
  u16*   YB    = (u16*)(ws + OFF_YB);
  u16*   HB    = (u16*)(ws + OFF_HB);
  u16*   VT    = (u16*)(ws + OFF_VT);
  u16*   CTX   = (u16*)(ws + OFF_CTX);
  float* TMP   = (float*)(ws + OFF_TMP);
  u16*   S     = (u16*)(ws + OFF_S);

  // 1) casts / weight prep
  cast_x_kernel<<<8192, 256, 0, stream>>>(x, XB);
  prep_w_kernel<<<1024, 256, 0, stream>>>(Wq, Wk, Wv, Wo, W1, W2, bq, bk, bv,
                                          WQKVT, WOT, W1T, W2T, BQKV);
  // 2) QKV projection: [32768,256] x [256,1536]
  gemm_bt<<<3072, 256, 0, stream>>>(XB, WQKVT, BQKV, nullptr, QKV,
                                    MTOK, 1536, 256, 0);
  // 3) V transpose per (b,w,h)
  transpose_v<<<4096, 256, 0, stream>>>(QKV, VT);
  // 4a) S = Q K^T (batched over 128 (b,w,h) blocks): M=512,N=512,K=256
  bgemm<<<2048, 256, 0, stream>>>(QKV,       786432, 256, 1536,
                                  QKV + 512, 786432, 256, 1536,
                                  S,         524288, 262144, 512,
                                  256, 4);
  // 4b) softmax rows of 512 (in place)
  softmax_kernel<<<16384, 256, 0, stream>>>(S);
  // 4c) CTX = P V (batched): M=512,N=256,K=512
  bgemm<<<1024, 256, 0, stream>>>(S,   524288, 262144, 512,
                                  VT,  262144, 131072, 512,
                                  CTX, 262144, 256, 512,
                                  512, 2);
  // 5) output projection: [32768,512] x [512,256]
  gemm_bt<<<512, 256, 0, stream>>>(CTX, WOT, bo, TMP, nullptr,
                                   MTOK, 256, 512, 0);
  // 6) residual + LN1 -> Y (f32) + YB (bf16)
  ln_kernel<<<8192, 256, 0, stream>>>(TMP, x, ln1g, ln1b, Y, YB);
  // 7) FF1 + ReLU: [32768,256] x [256,1024]
  gemm_bt<<<2048, 256, 0, stream>>>(YB, W1T, b1, nullptr, HB,
                                    MTOK, 1024, 256, 1);
  // 8) FF2: [32768,1024] x [1024,256]
  gemm_bt<<<512, 256, 0, stream>>>(HB, W2T, b2, TMP, nullptr,
                                   MTOK, 256, 1024, 0);
  // 9) residual + LN2 -> out
  ln_kernel<<<8192, 256, 0, stream>>>(TMP, Y, ln2g, ln2b, out, nullptr);
}